// Round 3
// baseline (1254.608 us; speedup 1.0000x reference)
//
#include <hip/hip_runtime.h>
#include <math.h>

// ================= degree + scan =================

__global__ void deg_count_k(const int* __restrict__ dst, int* __restrict__ cnt, int E) {
    int e = blockIdx.x * blockDim.x + threadIdx.x;
    if (e < E) atomicAdd(&cnt[dst[e]], 1);
}

// per-block exclusive scan of cnt -> row_off (local), block totals -> bsum
__global__ void scan_local_k(const int* __restrict__ cnt, int* __restrict__ row_off,
                             int* __restrict__ bsum, int n) {
    __shared__ int tmp[256];
    int t = threadIdx.x;
    int i = blockIdx.x * 256 + t;
    int v = (i < n) ? cnt[i] : 0;
    tmp[t] = v;
    __syncthreads();
    for (int off = 1; off < 256; off <<= 1) {
        int a = (t >= off) ? tmp[t - off] : 0;
        __syncthreads();
        tmp[t] += a;
        __syncthreads();
    }
    if (i < n) row_off[i] = tmp[t] - v;  // exclusive
    if (t == 255) bsum[blockIdx.x] = tmp[255];
}

// single-block exclusive scan of bsum (nb <= 256)
__global__ void scan_block_k(int* __restrict__ bsum, int nb) {
    __shared__ int tmp[256];
    int t = threadIdx.x;
    int v = (t < nb) ? bsum[t] : 0;
    tmp[t] = v;
    __syncthreads();
    for (int off = 1; off < 256; off <<= 1) {
        int a = (t >= off) ? tmp[t - off] : 0;
        __syncthreads();
        tmp[t] += a;
        __syncthreads();
    }
    if (t < nb) bsum[t] = tmp[t] - v;
}

__global__ void scan_add_k(int* __restrict__ row_off, const int* __restrict__ bsum,
                           int n, int E) {
    int i = blockIdx.x * 256 + threadIdx.x;
    if (i < n) row_off[i] += bsum[blockIdx.x];
    if (i == 0) row_off[n] = E;
}

__global__ void dinv_k(const int* __restrict__ cnt, float* __restrict__ dinv, int n) {
    int i = blockIdx.x * blockDim.x + threadIdx.x;
    if (i < n) dinv[i] = rsqrtf((float)(cnt[i] + 1));  // +1 = self-loop
}

// ================= bucket-sorted CSR build =================
// Bucket b = nodes [256b, 256(b+1)) owns contiguous csr segment
// [row_off[256b], row_off[256(b+1)}). Pack (local_node<<16)|src  (requires n<65536).

__global__ void bucket_scatter_k(const int* __restrict__ src, const int* __restrict__ dst,
                                 const int* __restrict__ row_off, int* __restrict__ bfill,
                                 unsigned int* __restrict__ bpk, int E) {
    int e = blockIdx.x * blockDim.x + threadIdx.x;
    if (e < E) {
        int d = dst[e];
        int b = d >> 8;
        int ln = d & 255;
        int base = row_off[b << 8];
        int pos = atomicAdd(&bfill[b], 1);
        bpk[base + pos] = ((unsigned)ln << 16) | (unsigned)src[e];
    }
}

#define BCAP 15360  // 60KB staging; bucket mean 8163, +80 sigma headroom

__global__ void bucket_build_k(const unsigned int* __restrict__ bpk,
                               const int* __restrict__ row_off,
                               int* __restrict__ csr, int n) {
    __shared__ int loff[256];
    __shared__ int lfill[256];
    __shared__ int scsr[BCAP];
    int b = blockIdx.x;
    int t = threadIdx.x;
    int node = (b << 8) + t;
    int node_hi = min((b + 1) << 8, n);
    int base = row_off[b << 8];
    loff[t] = (node < n) ? (row_off[node] - base) : 0;
    lfill[t] = 0;
    __syncthreads();
    int bsize = row_off[node_hi] - base;
    if (bsize <= BCAP) {
        for (int idx = t; idx < bsize; idx += 256) {
            unsigned u = bpk[base + idx];
            int ln = (int)(u >> 16);
            int sp = atomicAdd(&lfill[ln], 1);
            scsr[loff[ln] + sp] = (int)(u & 0xFFFFu);
        }
        __syncthreads();
        for (int idx = t; idx < bsize; idx += 256)
            csr[base + idx] = scsr[idx];
    } else {  // freak-large bucket: slow correct path
        for (int idx = t; idx < bsize; idx += 256) {
            unsigned u = bpk[base + idx];
            int ln = (int)(u >> 16);
            int sp = atomicAdd(&lfill[ln], 1);
            csr[base + loff[ln] + sp] = (int)(u & 0xFFFFu);
        }
    }
}

// ================= dense GEMMs (fp32 vector ALU), dinv-scaled epilogue =================

// hs[n,128] = (x[n,256] @ W[256,128]) * dinv[row]
__global__ void gemm1_k(const float* __restrict__ x, const float* __restrict__ W,
                        const float* __restrict__ dinv, float* __restrict__ hs, int n) {
    int r0 = blockIdx.x * 8;
    int t = threadIdx.x;  // 0..127 -> output column
    __shared__ float xs[8][256];
    for (int i = t; i < 8 * 256; i += 128) {
        int r = i >> 8, k = i & 255;
        int row = r0 + r;
        xs[r][k] = (row < n) ? x[(long long)row * 256 + k] : 0.0f;
    }
    __syncthreads();
    float acc[8] = {0, 0, 0, 0, 0, 0, 0, 0};
#pragma unroll 4
    for (int k = 0; k < 256; ++k) {
        float w = W[k * 128 + t];
#pragma unroll
        for (int r = 0; r < 8; ++r) acc[r] += xs[r][k] * w;
    }
#pragma unroll
    for (int r = 0; r < 8; ++r) {
        int row = r0 + r;
        if (row < n) hs[(long long)row * 128 + t] = acc[r] * dinv[row];
    }
}

// hs2[n,64] = (h1[n,128] @ W[128,64]) * dinv[row]
__global__ void gemm2_k(const float* __restrict__ h1, const float* __restrict__ W,
                        const float* __restrict__ dinv, float* __restrict__ hs2, int n) {
    int r0 = blockIdx.x * 8;
    int t = threadIdx.x;  // 0..63 -> output column
    __shared__ float xs[8][128];
    for (int i = t; i < 8 * 128; i += 64) {
        int r = i >> 7, k = i & 127;
        int row = r0 + r;
        xs[r][k] = (row < n) ? h1[(long long)row * 128 + k] : 0.0f;
    }
    __syncthreads();
    float acc[8] = {0, 0, 0, 0, 0, 0, 0, 0};
#pragma unroll 4
    for (int k = 0; k < 128; ++k) {
        float w = W[k * 64 + t];
#pragma unroll
        for (int r = 0; r < 8; ++r) acc[r] += xs[r][k] * w;
    }
#pragma unroll
    for (int r = 0; r < 8; ++r) {
        int row = r0 + r;
        if (row < n) hs2[(long long)row * 64 + t] = acc[r] * dinv[row];
    }
}

// ================= gather-side aggregation (no atomics) =================

// h1[i] = relu(dinv[i]*(hs[i] + sum_{j in N(i)} hs[j]) + b1)   C=128, 32 lanes/node
__global__ void gather1_k(const float* __restrict__ hs, const int* __restrict__ row_off,
                          const int* __restrict__ csr, const float* __restrict__ dinv,
                          const float* __restrict__ b1, float* __restrict__ h1, int n) {
    int g = threadIdx.x >> 5;
    int lane = threadIdx.x & 31;
    int i = blockIdx.x * 8 + g;
    if (i >= n) return;
    float4 acc = ((const float4*)(hs + (long long)i * 128))[lane];  // self term
    int beg = row_off[i], end = row_off[i + 1];
    int j = beg;
    for (; j + 4 <= end; j += 4) {
        int s0 = csr[j], s1 = csr[j + 1], s2 = csr[j + 2], s3 = csr[j + 3];
        float4 v0 = ((const float4*)(hs + (long long)s0 * 128))[lane];
        float4 v1 = ((const float4*)(hs + (long long)s1 * 128))[lane];
        float4 v2 = ((const float4*)(hs + (long long)s2 * 128))[lane];
        float4 v3 = ((const float4*)(hs + (long long)s3 * 128))[lane];
        acc.x += v0.x + v1.x + v2.x + v3.x;
        acc.y += v0.y + v1.y + v2.y + v3.y;
        acc.z += v0.z + v1.z + v2.z + v3.z;
        acc.w += v0.w + v1.w + v2.w + v3.w;
    }
    for (; j < end; ++j) {
        int s0 = csr[j];
        float4 v0 = ((const float4*)(hs + (long long)s0 * 128))[lane];
        acc.x += v0.x; acc.y += v0.y; acc.z += v0.z; acc.w += v0.w;
    }
    float di = dinv[i];
    float4 bb = ((const float4*)b1)[lane];
    float4 o;
    o.x = fmaxf(di * acc.x + bb.x, 0.0f);
    o.y = fmaxf(di * acc.y + bb.y, 0.0f);
    o.z = fmaxf(di * acc.z + bb.z, 0.0f);
    o.w = fmaxf(di * acc.w + bb.w, 0.0f);
    ((float4*)(h1 + (long long)i * 128))[lane] = o;
}

// logits -> pred/prob, C=64, 16 lanes/node. out[0:t)=pred, out[t:2t)=prob
__global__ void gather2_k(const float* __restrict__ hs2, const int* __restrict__ row_off,
                          const int* __restrict__ csr, const float* __restrict__ dinv,
                          const float* __restrict__ b2, float* __restrict__ out, int n) {
    int g = threadIdx.x >> 4;
    int lane = threadIdx.x & 15;
    int i = blockIdx.x * 16 + g;
    if (i >= n) return;
    float4 acc = ((const float4*)(hs2 + (long long)i * 64))[lane];  // self term
    int beg = row_off[i], end = row_off[i + 1];
    int j = beg;
    for (; j + 4 <= end; j += 4) {
        int s0 = csr[j], s1 = csr[j + 1], s2 = csr[j + 2], s3 = csr[j + 3];
        float4 v0 = ((const float4*)(hs2 + (long long)s0 * 64))[lane];
        float4 v1 = ((const float4*)(hs2 + (long long)s1 * 64))[lane];
        float4 v2 = ((const float4*)(hs2 + (long long)s2 * 64))[lane];
        float4 v3 = ((const float4*)(hs2 + (long long)s3 * 64))[lane];
        acc.x += v0.x + v1.x + v2.x + v3.x;
        acc.y += v0.y + v1.y + v2.y + v3.y;
        acc.z += v0.z + v1.z + v2.z + v3.z;
        acc.w += v0.w + v1.w + v2.w + v3.w;
    }
    for (; j < end; ++j) {
        int s0 = csr[j];
        float4 v0 = ((const float4*)(hs2 + (long long)s0 * 64))[lane];
        acc.x += v0.x; acc.y += v0.y; acc.z += v0.z; acc.w += v0.w;
    }
    float di = dinv[i];
    float4 bb = ((const float4*)b2)[lane];
    float lx = di * acc.x + bb.x;
    float ly = di * acc.y + bb.y;
    float lz = di * acc.z + bb.z;
    float lw = di * acc.w + bb.w;
    float4 p;
    p.x = 1.0f / (1.0f + expf(-lx));
    p.y = 1.0f / (1.0f + expf(-ly));
    p.z = 1.0f / (1.0f + expf(-lz));
    p.w = 1.0f / (1.0f + expf(-lw));
    long long total = (long long)n * 64;
    long long o0 = (long long)i * 64 + lane * 4;
    float4 pr;
    pr.x = (p.x > 0.5f) ? 1.0f : 0.0f;
    pr.y = (p.y > 0.5f) ? 1.0f : 0.0f;
    pr.z = (p.z > 0.5f) ? 1.0f : 0.0f;
    pr.w = (p.w > 0.5f) ? 1.0f : 0.0f;
    *(float4*)(out + o0) = pr;
    *(float4*)(out + total + o0) = p;
}

// ================= launch =================

extern "C" void kernel_launch(void* const* d_in, const int* in_sizes, int n_in,
                              void* d_out, int out_size, void* d_ws, size_t ws_size,
                              hipStream_t stream) {
    const float* x  = (const float*)d_in[0];
    const int*   ei = (const int*)d_in[1];
    const float* W1 = (const float*)d_in[2];
    const float* b1 = (const float*)d_in[3];
    const float* W2 = (const float*)d_in[4];
    const float* b2 = (const float*)d_in[5];
    float* out = (float*)d_out;

    const int n = in_sizes[0] / 256;   // 50000  (packing requires n < 65536)
    const int E = in_sizes[1] / 2;     // 1.6M
    const int* src = ei;
    const int* dst = ei + E;

    // ---- workspace carve-up (256B-aligned) ----
    char* base = (char*)d_ws;
    size_t off = 0;
    auto carve = [&](size_t bytes) -> void* {
        void* p = base + off;
        off = (off + bytes + 255) & ~(size_t)255;
        return p;
    };
    int*   cnt     = (int*)  carve((size_t)(n + 256) * sizeof(int)); // cnt[n] + bfill[256]
    int*   bfill   = cnt + n;
    int*   row_off = (int*)  carve((size_t)(n + 1) * sizeof(int));
    int*   bsum    = (int*)  carve(256 * sizeof(int));
    int*   csr     = (int*)  carve((size_t)E * sizeof(int));
    float* dinv    = (float*)carve((size_t)n * sizeof(float));
    float* hs0     = (float*)carve((size_t)n * 128 * sizeof(float));
    float* h1      = (float*)carve((size_t)n * 128 * sizeof(float));
    float* hs2     = (float*)carve((size_t)n * 64 * sizeof(float));
    // packed bucket buffer aliases hs0 (E*4B <= n*128*4B); consumed before gemm1 writes hs0
    unsigned int* bpk = (unsigned int*)hs0;

    const int nb = (n + 255) / 256;      // scan blocks / bucket count (196)

    hipMemsetAsync(cnt, 0, (size_t)(n + 256) * sizeof(int), stream);
    deg_count_k<<<(E + 255) / 256, 256, 0, stream>>>(dst, cnt, E);
    scan_local_k<<<nb, 256, 0, stream>>>(cnt, row_off, bsum, n);
    scan_block_k<<<1, 256, 0, stream>>>(bsum, nb);
    scan_add_k<<<nb, 256, 0, stream>>>(row_off, bsum, n, E);
    dinv_k<<<(n + 255) / 256, 256, 0, stream>>>(cnt, dinv, n);
    bucket_scatter_k<<<(E + 255) / 256, 256, 0, stream>>>(src, dst, row_off, bfill, bpk, E);
    bucket_build_k<<<nb, 256, 0, stream>>>(bpk, row_off, csr, n);

    gemm1_k<<<(n + 7) / 8, 128, 0, stream>>>(x, W1, dinv, hs0, n);
    gather1_k<<<(n + 7) / 8, 256, 0, stream>>>(hs0, row_off, csr, dinv, b1, h1, n);
    gemm2_k<<<(n + 7) / 8, 64, 0, stream>>>(h1, W2, dinv, hs2, n);
    gather2_k<<<(n + 15) / 16, 256, 0, stream>>>(hs2, row_off, csr, dinv, b2, out, n);
}

// Round 4
// 315.396 us; speedup vs baseline: 3.9779x; 3.9779x over previous
//
#include <hip/hip_runtime.h>
#include <math.h>

#define EPT 16
#define CHUNK (256 * EPT)  // 4096 edges per scatter block
#define BCAP 15360         // staging capacity per bucket (mean 8163, +80 sigma)

// ================= bucket-aggregated CSR build =================
// Bucket b = nodes [256b, 256(b+1)). Requires n < 65536 (pack (local<<16)|src).

// per-bucket edge counts (LDS histogram per block, 1 global atomic per bucket per block)
__global__ void bucket_hist_k(const int* __restrict__ dst, int* __restrict__ bcnt,
                              int E, int nb) {
    __shared__ int h[256];
    int t = threadIdx.x;
    h[t] = 0;
    __syncthreads();
    for (int e = blockIdx.x * blockDim.x + t; e < E; e += gridDim.x * blockDim.x)
        atomicAdd(&h[dst[e] >> 8], 1);
    __syncthreads();
    if (t < nb && h[t]) atomicAdd(&bcnt[t], h[t]);
}

// exclusive scan of bcnt[nb] -> bbase[nb+1]   (nb <= 256, single block)
__global__ void bucket_base_k(const int* __restrict__ bcnt, int* __restrict__ bbase, int nb) {
    __shared__ int tmp[256];
    int t = threadIdx.x;
    int v = (t < nb) ? bcnt[t] : 0;
    tmp[t] = v;
    __syncthreads();
    for (int off = 1; off < 256; off <<= 1) {
        int a = (t >= off) ? tmp[t - off] : 0;
        __syncthreads();
        tmp[t] += a;
        __syncthreads();
    }
    if (t < nb) bbase[t] = tmp[t] - v;
    if (t == nb - 1) bbase[nb] = tmp[t];  // == E
}

// scatter packed edges into bucket segments; one block = 4096 edges,
// block reserves per-bucket ranges with ONE global atomic per touched bucket
__global__ void bucket_scatter_k(const int* __restrict__ src, const int* __restrict__ dst,
                                 const int* __restrict__ bbase, int* __restrict__ bfill,
                                 unsigned int* __restrict__ bpk, int E) {
    __shared__ int hist[256], gofs[256], lfill[256];
    int t = threadIdx.x;
    int base = blockIdx.x * CHUNK;
    hist[t] = 0;
    lfill[t] = 0;
    __syncthreads();
    int ds[EPT], ss[EPT];
#pragma unroll
    for (int i = 0; i < EPT; ++i) {
        int e = base + i * 256 + t;
        if (e < E) {
            ds[i] = dst[e];
            ss[i] = src[e];
            atomicAdd(&hist[ds[i] >> 8], 1);
        } else {
            ds[i] = -1;
        }
    }
    __syncthreads();
    if (hist[t]) gofs[t] = atomicAdd(&bfill[t], hist[t]);
    __syncthreads();
#pragma unroll
    for (int i = 0; i < EPT; ++i) {
        if (ds[i] >= 0) {
            int b = ds[i] >> 8;
            int p = atomicAdd(&lfill[b], 1);
            bpk[bbase[b] + gofs[b] + p] = ((unsigned)(ds[i] & 255) << 16) | (unsigned)ss[i];
        }
    }
}

// one block per bucket: histogram local nodes -> dinv + row_off, LDS counting-sort,
// coalesced csr (ushort) write
__global__ void bucket_build_k(const unsigned int* __restrict__ bpk,
                               const int* __restrict__ bbase,
                               unsigned short* __restrict__ csr, int* __restrict__ row_off,
                               float* __restrict__ dinv, int n, int E) {
    __shared__ int hist[256], loff[256], lfill[256], tmp[256];
    __shared__ unsigned short scsr[BCAP];
    int b = blockIdx.x, t = threadIdx.x;
    int base = bbase[b];
    int bsize = bbase[b + 1] - base;
    hist[t] = 0;
    lfill[t] = 0;
    __syncthreads();
    for (int idx = t; idx < bsize; idx += 256)
        atomicAdd(&hist[bpk[base + idx] >> 16], 1);
    __syncthreads();
    int deg = hist[t];
    tmp[t] = deg;
    __syncthreads();
    for (int off = 1; off < 256; off <<= 1) {
        int a = (t >= off) ? tmp[t - off] : 0;
        __syncthreads();
        tmp[t] += a;
        __syncthreads();
    }
    loff[t] = tmp[t] - deg;  // exclusive
    int node = (b << 8) + t;
    if (node < n) {
        row_off[node] = base + loff[t];
        dinv[node] = rsqrtf((float)(deg + 1));  // +1 self-loop
    }
    if (node == n - 1) row_off[n] = E;
    __syncthreads();
    if (bsize <= BCAP) {
        for (int idx = t; idx < bsize; idx += 256) {
            unsigned u = bpk[base + idx];
            int ln = (int)(u >> 16);
            int sp = atomicAdd(&lfill[ln], 1);
            scsr[loff[ln] + sp] = (unsigned short)(u & 0xFFFFu);
        }
        __syncthreads();
        for (int idx = t; idx < bsize; idx += 256)
            csr[base + idx] = scsr[idx];
    } else {  // freak-large bucket: slow correct path
        for (int idx = t; idx < bsize; idx += 256) {
            unsigned u = bpk[base + idx];
            int ln = (int)(u >> 16);
            int sp = atomicAdd(&lfill[ln], 1);
            csr[base + loff[ln] + sp] = (unsigned short)(u & 0xFFFFu);
        }
    }
}

// ================= dense GEMMs (fp32 vector ALU), dinv-scaled epilogue =================

// hs[n,128] = (x[n,256] @ W[256,128]) * dinv[row]
__global__ void gemm1_k(const float* __restrict__ x, const float* __restrict__ W,
                        const float* __restrict__ dinv, float* __restrict__ hs, int n) {
    int r0 = blockIdx.x * 8;
    int t = threadIdx.x;  // 0..127 -> output column
    __shared__ float xs[8][256];
    for (int i = t; i < 8 * 256; i += 128) {
        int r = i >> 8, k = i & 255;
        int row = r0 + r;
        xs[r][k] = (row < n) ? x[(long long)row * 256 + k] : 0.0f;
    }
    __syncthreads();
    float acc[8] = {0, 0, 0, 0, 0, 0, 0, 0};
#pragma unroll 4
    for (int k = 0; k < 256; ++k) {
        float w = W[k * 128 + t];
#pragma unroll
        for (int r = 0; r < 8; ++r) acc[r] += xs[r][k] * w;
    }
#pragma unroll
    for (int r = 0; r < 8; ++r) {
        int row = r0 + r;
        if (row < n) hs[(long long)row * 128 + t] = acc[r] * dinv[row];
    }
}

// hs2[n,64] = (h1[n,128] @ W[128,64]) * dinv[row]
__global__ void gemm2_k(const float* __restrict__ h1, const float* __restrict__ W,
                        const float* __restrict__ dinv, float* __restrict__ hs2, int n) {
    int r0 = blockIdx.x * 8;
    int t = threadIdx.x;  // 0..63 -> output column
    __shared__ float xs[8][128];
    for (int i = t; i < 8 * 128; i += 64) {
        int r = i >> 7, k = i & 127;
        int row = r0 + r;
        xs[r][k] = (row < n) ? h1[(long long)row * 128 + k] : 0.0f;
    }
    __syncthreads();
    float acc[8] = {0, 0, 0, 0, 0, 0, 0, 0};
#pragma unroll 4
    for (int k = 0; k < 128; ++k) {
        float w = W[k * 64 + t];
#pragma unroll
        for (int r = 0; r < 8; ++r) acc[r] += xs[r][k] * w;
    }
#pragma unroll
    for (int r = 0; r < 8; ++r) {
        int row = r0 + r;
        if (row < n) hs2[(long long)row * 64 + t] = acc[r] * dinv[row];
    }
}

// ================= gather-side aggregation (no atomics) =================

// h1[i] = relu(dinv[i]*(hs[i] + sum_{j in N(i)} hs[j]) + b1)   C=128, 32 lanes/node
__global__ void gather1_k(const float* __restrict__ hs, const int* __restrict__ row_off,
                          const unsigned short* __restrict__ csr, const float* __restrict__ dinv,
                          const float* __restrict__ b1, float* __restrict__ h1, int n) {
    int g = threadIdx.x >> 5;
    int lane = threadIdx.x & 31;
    int i = blockIdx.x * 8 + g;
    if (i >= n) return;
    float4 acc = ((const float4*)(hs + (long long)i * 128))[lane];  // self term
    int beg = row_off[i], end = row_off[i + 1];
    int j = beg;
    for (; j + 4 <= end; j += 4) {
        int s0 = csr[j], s1 = csr[j + 1], s2 = csr[j + 2], s3 = csr[j + 3];
        float4 v0 = ((const float4*)(hs + (long long)s0 * 128))[lane];
        float4 v1 = ((const float4*)(hs + (long long)s1 * 128))[lane];
        float4 v2 = ((const float4*)(hs + (long long)s2 * 128))[lane];
        float4 v3 = ((const float4*)(hs + (long long)s3 * 128))[lane];
        acc.x += v0.x + v1.x + v2.x + v3.x;
        acc.y += v0.y + v1.y + v2.y + v3.y;
        acc.z += v0.z + v1.z + v2.z + v3.z;
        acc.w += v0.w + v1.w + v2.w + v3.w;
    }
    for (; j < end; ++j) {
        int s0 = csr[j];
        float4 v0 = ((const float4*)(hs + (long long)s0 * 128))[lane];
        acc.x += v0.x; acc.y += v0.y; acc.z += v0.z; acc.w += v0.w;
    }
    float di = dinv[i];
    float4 bb = ((const float4*)b1)[lane];
    float4 o;
    o.x = fmaxf(di * acc.x + bb.x, 0.0f);
    o.y = fmaxf(di * acc.y + bb.y, 0.0f);
    o.z = fmaxf(di * acc.z + bb.z, 0.0f);
    o.w = fmaxf(di * acc.w + bb.w, 0.0f);
    ((float4*)(h1 + (long long)i * 128))[lane] = o;
}

// logits -> pred/prob, C=64, 16 lanes/node. out[0:t)=pred, out[t:2t)=prob
__global__ void gather2_k(const float* __restrict__ hs2, const int* __restrict__ row_off,
                          const unsigned short* __restrict__ csr, const float* __restrict__ dinv,
                          const float* __restrict__ b2, float* __restrict__ out, int n) {
    int g = threadIdx.x >> 4;
    int lane = threadIdx.x & 15;
    int i = blockIdx.x * 16 + g;
    if (i >= n) return;
    float4 acc = ((const float4*)(hs2 + (long long)i * 64))[lane];  // self term
    int beg = row_off[i], end = row_off[i + 1];
    int j = beg;
    for (; j + 4 <= end; j += 4) {
        int s0 = csr[j], s1 = csr[j + 1], s2 = csr[j + 2], s3 = csr[j + 3];
        float4 v0 = ((const float4*)(hs2 + (long long)s0 * 64))[lane];
        float4 v1 = ((const float4*)(hs2 + (long long)s1 * 64))[lane];
        float4 v2 = ((const float4*)(hs2 + (long long)s2 * 64))[lane];
        float4 v3 = ((const float4*)(hs2 + (long long)s3 * 64))[lane];
        acc.x += v0.x + v1.x + v2.x + v3.x;
        acc.y += v0.y + v1.y + v2.y + v3.y;
        acc.z += v0.z + v1.z + v2.z + v3.z;
        acc.w += v0.w + v1.w + v2.w + v3.w;
    }
    for (; j < end; ++j) {
        int s0 = csr[j];
        float4 v0 = ((const float4*)(hs2 + (long long)s0 * 64))[lane];
        acc.x += v0.x; acc.y += v0.y; acc.z += v0.z; acc.w += v0.w;
    }
    float di = dinv[i];
    float4 bb = ((const float4*)b2)[lane];
    float lx = di * acc.x + bb.x;
    float ly = di * acc.y + bb.y;
    float lz = di * acc.z + bb.z;
    float lw = di * acc.w + bb.w;
    float4 p;
    p.x = 1.0f / (1.0f + expf(-lx));
    p.y = 1.0f / (1.0f + expf(-ly));
    p.z = 1.0f / (1.0f + expf(-lz));
    p.w = 1.0f / (1.0f + expf(-lw));
    long long total = (long long)n * 64;
    long long o0 = (long long)i * 64 + lane * 4;
    float4 pr;
    pr.x = (p.x > 0.5f) ? 1.0f : 0.0f;
    pr.y = (p.y > 0.5f) ? 1.0f : 0.0f;
    pr.z = (p.z > 0.5f) ? 1.0f : 0.0f;
    pr.w = (p.w > 0.5f) ? 1.0f : 0.0f;
    *(float4*)(out + o0) = pr;
    *(float4*)(out + total + o0) = p;
}

// ================= launch =================

extern "C" void kernel_launch(void* const* d_in, const int* in_sizes, int n_in,
                              void* d_out, int out_size, void* d_ws, size_t ws_size,
                              hipStream_t stream) {
    const float* x  = (const float*)d_in[0];
    const int*   ei = (const int*)d_in[1];
    const float* W1 = (const float*)d_in[2];
    const float* b1 = (const float*)d_in[3];
    const float* W2 = (const float*)d_in[4];
    const float* b2 = (const float*)d_in[5];
    float* out = (float*)d_out;

    const int n = in_sizes[0] / 256;   // 50000 (packing requires n < 65536)
    const int E = in_sizes[1] / 2;     // 1.6M
    const int* src = ei;
    const int* dst = ei + E;

    // ---- workspace carve-up (256B-aligned) ----
    char* base = (char*)d_ws;
    size_t off = 0;
    auto carve = [&](size_t bytes) -> void* {
        void* p = base + off;
        off = (off + bytes + 255) & ~(size_t)255;
        return p;
    };
    int*   bcnt    = (int*)  carve(512 * sizeof(int));  // bcnt[256] + bfill[256]
    int*   bfill   = bcnt + 256;
    int*   bbase   = (int*)  carve(257 * sizeof(int));
    int*   row_off = (int*)  carve((size_t)(n + 1) * sizeof(int));
    unsigned short* csr = (unsigned short*)carve((size_t)E * sizeof(unsigned short));
    float* dinv    = (float*)carve((size_t)n * sizeof(float));
    float* hs0     = (float*)carve((size_t)n * 128 * sizeof(float));
    float* h1      = (float*)carve((size_t)n * 128 * sizeof(float));
    float* hs2     = (float*)carve((size_t)n * 64 * sizeof(float));
    // packed bucket buffer aliases hs0 (E*4B <= n*128*4B); consumed before gemm1 writes hs0
    unsigned int* bpk = (unsigned int*)hs0;

    const int nb = (n + 255) / 256;  // bucket count (196)

    hipMemsetAsync(bcnt, 0, 512 * sizeof(int), stream);
    bucket_hist_k<<<512, 256, 0, stream>>>(dst, bcnt, E, nb);
    bucket_base_k<<<1, 256, 0, stream>>>(bcnt, bbase, nb);
    bucket_scatter_k<<<(E + CHUNK - 1) / CHUNK, 256, 0, stream>>>(src, dst, bbase, bfill, bpk, E);
    bucket_build_k<<<nb, 256, 0, stream>>>(bpk, bbase, csr, row_off, dinv, n, E);

    gemm1_k<<<(n + 7) / 8, 128, 0, stream>>>(x, W1, dinv, hs0, n);
    gather1_k<<<(n + 7) / 8, 256, 0, stream>>>(hs0, row_off, csr, dinv, b1, h1, n);
    gemm2_k<<<(n + 7) / 8, 64, 0, stream>>>(h1, W2, dinv, hs2, n);
    gather2_k<<<(n + 15) / 16, 256, 0, stream>>>(hs2, row_off, csr, dinv, b2, out, n);
}